// Round 14
// baseline (370.556 us; speedup 1.0000x reference)
//
#include <hip/hip_runtime.h>
#include <math.h>

#define PI_F      3.14159265358979323846f
#define HALFPI_F  1.57079632679489661923f
#define TWOPI_F   6.28318530717958647692f
#define ANG_F     0.8944271909999159f
#define RT2H      0.70710678118654752f

// ---- staging: [NP partitions][PSZ doubles], partition stride 4KiB ----
#define NP       32
#define PSZ      512
#define PP_PIX   0              // [4]
#define PP_MAG   4              // [18]
#define PP_HISQ  22             // [1]
#define PP_PMAG  23             // [12]
#define PP_IMM   35             // [15]
#define PP_C0    50             // [4][16]
#define PP_CR    114            // [4][16]
#define PP_CX    178            // [3][16]
#define PP_CRX   226            // [4][32]
#define PP_CR5   354            // [25]
#define SG_ACP   (NP * PSZ)
#define ACPART   8
#define ACSTRIDE 64
#define NSTG     (SG_ACP + ACPART * 21 * ACSTRIDE)

enum { MG_HI = 0, MG_IM, MG_BAND, MG_EMBED_BAND, MG_EMBED_LO, MG_LORES, MG_IMF4 };
enum { WB_WRITE = 0, WB_WRITE_MAG, WB_WRITE_IM, WB_RED_HI, WB_RED_ABSRE, WB_PDOTS };

__device__ __forceinline__ int sfreq(int k, int N) { return (k < (N >> 1)) ? k : k - N; }
__device__ __forceinline__ int skx(int i) { return i + (i >> 4); }

// sqrt(rc(x)) = cos(pi/2 * clip(-x,0,1));  sqrt(1-rc(x)) = sin(pi/2 * clip(-x,0,1))
__device__ __forceinline__ float d_clip(float x) { return fminf(fmaxf(-x, 0.0f), 1.0f); }
__device__ __forceinline__ float d_hi(float x) { return __cosf(HALFPI_F * d_clip(x)); }
__device__ __forceinline__ float d_lo(float x) { return __sinf(HALFPI_F * d_clip(x)); }

__device__ __forceinline__ float d_amaskA(int fy, int fx, float rinv, int b) {
  float d;
  if (b == 0)      d = (float)fx;
  else if (b == 1) d = ((float)fx + (float)fy) * RT2H;
  else if (b == 2) d = (float)fy;
  else             d = ((float)fy - (float)fx) * RT2H;
  float c = d * rinv;
  return (c > 0.0f) ? 2.0f * ANG_F * c * c * c : 0.0f;
}
// recon mask at native size H (lr = lograd at H-grid)
__device__ __forceinline__ float d_mm_a(int fy, int fx, int H, float lr, float rinv) {
  float hm = d_hi(lr + 1.0f);
  float hm2 = hm * hm;
  float lo0 = d_lo(lr);
  int gfy = (fy == -(H >> 1)) ? fy : -fy;
  int gfx = (fx == -(H >> 1)) ? fx : -fx;
  float fxc = (float)fx, fyc = (float)fy, gxc = (float)gfx, gyc = (float)gfy;
  float msum = 0.0f;
  #pragma unroll
  for (int b = 0; b < 4; b++) {
    float d1, d2;
    if (b == 0)      { d1 = fxc;                d2 = gxc; }
    else if (b == 1) { d1 = (fxc + fyc) * RT2H; d2 = (gxc + gyc) * RT2H; }
    else if (b == 2) { d1 = fyc;                d2 = gyc; }
    else             { d1 = (fyc - fxc) * RT2H; d2 = (gyc - gxc) * RT2H; }
    float c1 = d1 * rinv, c2 = d2 * rinv;
    float A1 = ANG_F * c1 * c1 * c1;
    float T1 = (c1 > 0.0f) ? A1 : 0.0f;
    float A2 = ANG_F * c2 * c2 * c2;
    float T2 = (c2 > 0.0f) ? A2 : 0.0f;
    msum += A1 * (T1 - T2);
  }
  return lo0 * hm2 * msum;
}
// accumulated im-chain mask at native size 1<<l2n (runtime)
__device__ __forceinline__ float d_G_rt(int fy, int fx, int l2n, float lrb, float rinv) {
  if (fy == 0 && fx == 0) return 0.0f;
  float g = d_mm_a(fy, fx, 1 << l2n, lrb + (float)(1 - l2n), rinv);
  float chain = 1.0f;
  for (int lj = l2n - 1; lj >= 6; lj--) {
    int h = 1 << (lj - 1);
    if (fy < -h || fy >= h || fx < -h || fx >= h) break;
    float lrj = lrb + (float)(1 - lj);
    chain *= d_lo(lrj);
    if (lj > 6) g += chain * d_mm_a(fy, fx, 1 << lj, lrj, rinv);
    else g += chain * d_lo(lrb - 5.0f);
  }
  return g;
}
__device__ __forceinline__ float d_cumlo(float lrb, int s) {
  float m = 1.0f;
  for (int j = 0; j <= s; j++) m *= d_lo(lrb - 9.0f + (float)j);
  return m;
}
__device__ __forceinline__ unsigned fkey(float f) {
  unsigned u = __float_as_uint(f);
  return (u & 0x80000000u) ? ~u : (u | 0x80000000u);
}
__device__ __forceinline__ float funkey(unsigned k) {
  return (k & 0x80000000u) ? __uint_as_float(k & 0x7FFFFFFFu) : __uint_as_float(~k);
}
__device__ __forceinline__ int sidx(int o) {
  int dy = o / 9 - 4, dx = o - (o / 9) * 9 - 4;
  if (dy < 0 || (dy == 0 && dx < 0)) { dy = -dy; dx = -dx; }
  return (dy == 0) ? dx : 5 + (dy - 1) * 9 + dx + 4;
}

template<int K>
__device__ __forceinline__ void blk_reduce(float* v, float* red) {
  int tid = threadIdx.x, wave = tid >> 6, lane = tid & 63;
  #pragma unroll
  for (int k = 0; k < K; k++) {
    float x = v[k];
    #pragma unroll
    for (int o = 32; o; o >>= 1) x += __shfl_down(x, o, 64);
    if (lane == 0) red[wave * K + k] = x;
  }
  __syncthreads();
  if (tid < K) red[tid] = red[tid] + red[K + tid] + red[2 * K + tid] + red[3 * K + tid];
}

// ================= FFT core (Stockham, radix-4 with leading radix-2) =================
template<int N> struct FftConst {
  static constexpr int L2N = (N == 64) ? 6 : (N == 128) ? 7 : (N == 256) ? 8 : (N == 512) ? 9 : 10;
  static constexpr int TPR = (N / 4 >= 256) ? 256 : ((N / 4 < 16) ? 16 : N / 4);
  static constexpr int RPB = 256 / TPR;
  static constexpr int BUF = N + (N >> 4);
};

template<int N, bool INV>
__device__ __forceinline__ float2* fft_core(float2* A, float2* B, const float2* tw, int tr) {
  constexpr int TPR = FftConst<N>::TPR;
  constexpr int L2N = FftConst<N>::L2N;
  float2* src = A; float2* dst = B;
  if constexpr (L2N & 1) {
    for (int t = tr; t < (N >> 1); t += TPR) {
      float2 w = tw[t];
      float cv = w.x, sv = INV ? w.y : -w.y;
      float2 a = src[skx(t)];
      float2 b = src[skx(t + (N >> 1))];
      float dx = a.x - b.x, dy = a.y - b.y;
      dst[skx(2 * t)] = make_float2(a.x + b.x, a.y + b.y);
      dst[skx(2 * t + 1)] = make_float2(dx * cv - dy * sv, dx * sv + dy * cv);
    }
    __syncthreads();
    float2* tmp = src; src = dst; dst = tmp;
  }
  #pragma unroll
  for (int st = (L2N & 1); st < L2N; st += 2) {
    for (int t = tr; t < (N >> 2); t += TPR) {
      int p = t >> st;
      int q = t & ((1 << st) - 1);
      int i0 = q + (p << st);
      float2 x0 = src[skx(i0)];
      float2 x1 = src[skx(i0 + (N >> 2))];
      float2 x2 = src[skx(i0 + (N >> 1))];
      float2 x3 = src[skx(i0 + 3 * (N >> 2))];
      float2 w = tw[p << st];
      float c1 = w.x, s1 = INV ? w.y : -w.y;
      float c2 = c1 * c1 - s1 * s1, s2 = 2.f * c1 * s1;
      float c3 = c2 * c1 - s2 * s1, s3 = c2 * s1 + s2 * c1;
      float e0x = x0.x + x2.x, e0y = x0.y + x2.y;
      float e1x = x0.x - x2.x, e1y = x0.y - x2.y;
      float o0x = x1.x + x3.x, o0y = x1.y + x3.y;
      float d1x = x1.x - x3.x, d1y = x1.y - x3.y;
      float o1x, o1y;
      if constexpr (INV) { o1x = -d1y; o1y = d1x; }
      else               { o1x = d1y;  o1y = -d1x; }
      float t1x = e1x + o1x, t1y = e1y + o1y;
      float t2x = e0x - o0x, t2y = e0y - o0y;
      float t3x = e1x - o1x, t3y = e1y - o1y;
      int o = q + (p << (st + 2));
      int s = 1 << st;
      dst[skx(o)]         = make_float2(e0x + o0x, e0y + o0y);
      dst[skx(o + s)]     = make_float2(t1x * c1 - t1y * s1, t1x * s1 + t1y * c1);
      dst[skx(o + 2 * s)] = make_float2(t2x * c2 - t2y * s2, t2x * s2 + t2y * c2);
      dst[skx(o + 3 * s)] = make_float2(t3x * c3 - t3y * s3, t3x * s3 + t3y * c3);
    }
    __syncthreads();
    float2* tmp = src; src = dst; dst = tmp;
  }
  return src;
}

// ---- mega tables ----
struct MAt {
  const float2* S;
  const float2* twg;
  float2* out[24];
  int boff[25];
  signed char mode[24], scale[24], aux[24], l2n[24];
  int np;
};
struct MBt {
  const float2* twg;
  double* stg;
  float2* pl[24];
  const float2* Bp12[12];
  int boff[25];
  int redo[24];
  signed char wmode[24], scale[24], aux[24], l2n[24];
  int np;
};
struct TIt {
  float2* pl[24];
  int toff[25];
  signed char l2n[24];
  int np;
};
struct ACt { const float2* in[21]; signed char pi[21], mode[21], l2n[21]; };
struct GRt { const float2* bp[4][4]; };

__device__ __forceinline__ float2 loadS(const float2* S, int fy, int fx, int mode, int s, int b, int l2n) {
  if (mode == MG_EMBED_BAND || mode == MG_EMBED_LO) {
    int q = 1 << (l2n - 2);
    if (fy < -q || fy >= q || fx < -q || fx >= q) return make_float2(0.f, 0.f);
  }
  int U = fx >= 0 ? fx : fx + 1024;
  int V = fy >= 0 ? fy : fy + 1024;
  float2 v = S[(size_t)U * 1024 + V];
  float r2 = (float)(fy * fy + fx * fx);
  bool dc = (r2 == 0.0f);
  float lrb = dc ? 0.0f : 0.5f * __log2f(r2);
  float rinv = dc ? 0.0f : rsqrtf(r2);
  float m;
  switch (mode) {
    case MG_HI:
      m = d_hi(lrb - 9.0f);
      return make_float2(v.x * m, v.y * m);
    case MG_IM:
      m = d_cumlo(lrb, s) * d_G_rt(fy, fx, l2n, lrb, rinv);
      return make_float2(v.x * m, v.y * m);
    case MG_BAND:
      m = d_cumlo(lrb, s) * d_hi(lrb + (float)s - 8.0f) * d_amaskA(fy, fx, rinv, b);
      return make_float2(-v.y * m, v.x * m);
    case MG_EMBED_BAND:
      m = d_cumlo(lrb, s + 1) * d_hi(lrb + (float)s - 7.0f) * d_amaskA(fy, fx, rinv, b);
      return make_float2(-v.y * m, v.x * m);
    case MG_EMBED_LO:
    case MG_LORES:
      if (dc) return make_float2(0.f, 0.f);
      m = d_cumlo(lrb, 4);
      return make_float2(v.x * m, v.y * m);
    default:  // MG_IMF4
      if (dc) return make_float2(0.f, 0.f);
      m = d_cumlo(lrb, 4) * d_lo(lrb - 5.0f);
      return make_float2(v.x * m, v.y * m);
  }
}

// mega passA: masked load from S -> inverse row FFT -> write
__global__ __launch_bounds__(256) void k_megaA(MAt p) {
  __shared__ float2 shAB[2176];
  __shared__ float2 tw[512];
  int bx = blockIdx.x;
  int pl = 0;
  while (pl + 1 < p.np && bx >= p.boff[pl + 1]) pl++;
  int rb_ = bx - p.boff[pl];
  int l2n = p.l2n[pl];
  int N = 1 << l2n;
  int TPR = (N >= 1024) ? 256 : ((N >> 2) < 16 ? 16 : (N >> 2));
  int RPB = 256 / TPR;
  int BUF = N + (N >> 4);
  int tid = threadIdx.x;
  for (int k = tid; k < (N >> 1); k += 256) tw[k] = p.twg[k << (10 - l2n)];
  int rl = tid / TPR, tr = tid % TPR;
  int row = rb_ * RPB + rl;
  int mode = p.mode[pl], s = p.scale[pl], b = p.aux[pl];
  float2* A = shAB + rl * BUF;
  float2* Bb = shAB + 1088 + rl * BUF;
  int fx = sfreq(row, N);
  for (int i = tr; i < N; i += TPR) A[skx(i)] = loadS(p.S, sfreq(i, N), fx, mode, s, b, l2n);
  __syncthreads();
  float2* res;
  switch (l2n) {
    case 10: res = fft_core<1024, true>(A, Bb, tw, tr); break;
    case 9:  res = fft_core<512, true>(A, Bb, tw, tr); break;
    case 8:  res = fft_core<256, true>(A, Bb, tw, tr); break;
    case 7:  res = fft_core<128, true>(A, Bb, tw, tr); break;
    default: res = fft_core<64, true>(A, Bb, tw, tr); break;
  }
  float sc = 1.0f / (float)N;
  float2* o = p.out[pl] + (size_t)row * N;
  for (int i = tr; i < N; i += TPR) {
    float2 v = res[skx(i)];
    o[i] = make_float2(v.x * sc, v.y * sc);
  }
}

// mega passB: plain load -> inverse row FFT -> in-place write + fused stats.
// Band planes (WB_WRITE_MAG) are written as (re, mag) pairs: nothing downstream needs im.
__global__ __launch_bounds__(256) void k_megaB(MBt p) {
  __shared__ float2 shAB[2176];
  __shared__ float2 tw[512];
  __shared__ float red[52];
  int bx = blockIdx.x;
  int pl = 0;
  while (pl + 1 < p.np && bx >= p.boff[pl + 1]) pl++;
  int rb_ = bx - p.boff[pl];
  int l2n = p.l2n[pl];
  int N = 1 << l2n;
  int TPR = (N >= 1024) ? 256 : ((N >> 2) < 16 ? 16 : (N >> 2));
  int RPB = 256 / TPR;
  int BUF = N + (N >> 4);
  int tid = threadIdx.x;
  double* base = p.stg + (size_t)(bx & (NP - 1)) * PSZ;
  for (int k = tid; k < (N >> 1); k += 256) tw[k] = p.twg[k << (10 - l2n)];
  int rl = tid / TPR, tr = tid % TPR;
  int row = rb_ * RPB + rl;
  float2* pln = p.pl[pl];
  const float2* in = pln + (size_t)row * N;
  float2* A = shAB + rl * BUF;
  float2* Bb = shAB + 1088 + rl * BUF;
  for (int i = tr; i < N; i += TPR) A[skx(i)] = in[i];
  __syncthreads();
  float2* res;
  switch (l2n) {
    case 10: res = fft_core<1024, true>(A, Bb, tw, tr); break;
    case 9:  res = fft_core<512, true>(A, Bb, tw, tr); break;
    case 8:  res = fft_core<256, true>(A, Bb, tw, tr); break;
    case 7:  res = fft_core<128, true>(A, Bb, tw, tr); break;
    default: res = fft_core<64, true>(A, Bb, tw, tr); break;
  }
  float sc = 1.0f / (float)N;
  int wmode = p.wmode[pl];
  int s = p.scale[pl], b = p.aux[pl];
  if (wmode == WB_WRITE || wmode == WB_WRITE_MAG || wmode == WB_WRITE_IM) {
    float2* o = pln + (size_t)row * N;
    float a0 = 0.f, a1 = 0.f, a2 = 0.f;
    for (int i = tr; i < N; i += TPR) {
      float2 v = res[skx(i)];
      v.x *= sc; v.y *= sc;
      if (wmode == WB_WRITE_MAG) {
        float mag = sqrtf(v.x * v.x + v.y * v.y);
        o[i] = make_float2(v.x, mag);          // (re, mag) pack
        a0 += mag;
      } else {
        o[i] = v;
        if (wmode == WB_WRITE_IM) { float v2 = v.x * v.x; a0 += v2; a1 += v2 * v.x; a2 += v2 * v2; }
      }
    }
    if (wmode == WB_WRITE_MAG) {
      float acc[1] = {a0}; blk_reduce<1>(acc, red);
      if (tid == 0) atomicAdd(&base[p.redo[pl]], (double)red[0]);
    } else if (wmode == WB_WRITE_IM) {
      float acc[3] = {a0, a1, a2}; blk_reduce<3>(acc, red);
      if (tid < 3) atomicAdd(&base[p.redo[pl] + tid], (double)red[tid]);
    }
  } else if (wmode == WB_RED_HI) {
    float a0 = 0.f, a1 = 0.f;
    for (int i = tr; i < N; i += TPR) {
      float v = res[skx(i)].x * sc;
      a0 += fabsf(v); a1 += v * v;
    }
    float acc[2] = {a0, a1}; blk_reduce<2>(acc, red);
    if (tid == 0) atomicAdd(&base[PP_MAG], (double)red[0]);
    if (tid == 1) atomicAdd(&base[PP_HISQ], (double)red[1]);
  } else if (wmode == WB_RED_ABSRE) {
    float a0 = 0.f;
    for (int i = tr; i < N; i += TPR) a0 += fabsf(res[skx(i)].x * sc);
    float acc[1] = {a0}; blk_reduce<1>(acc, red);
    if (tid == 0) atomicAdd(&base[p.redo[pl]], (double)red[0]);
  } else {  // WB_PDOTS (Bp12 planes are (re,mag) packed)
    float acc[13];
    #pragma unroll
    for (int k = 0; k < 13; k++) acc[k] = 0.f;
    for (int i = tr; i < N; i += TPR) {
      float2 v = res[skx(i)];
      v.x *= sc; v.y *= sc;
      float mag = sqrtf(v.x * v.x + v.y * v.y);
      float rr = 0.f, ri = 0.f;
      if (mag > 0.f) { rr = (v.y * v.y - v.x * v.x) / mag; ri = 2.f * v.x * v.y / mag; }
      size_t idx = (size_t)row * N + i;
      #pragma unroll
      for (int c = 0; c < 4; c++) {
        float2 bv = p.Bp12[s * 4 + c][idx];
        acc[c] += bv.y * mag;
        acc[4 + c] += bv.x * rr;
        acc[8 + c] += bv.x * ri;
      }
      acc[12] += mag;
    }
    blk_reduce<13>(acc, red);
    if (tid < 4) atomicAdd(&base[PP_CX + s * 16 + tid * 4 + b], (double)red[tid]);
    else if (tid < 8) atomicAdd(&base[PP_CRX + s * 32 + (tid - 4) * 8 + b], (double)red[tid]);
    else if (tid < 12) atomicAdd(&base[PP_CRX + s * 32 + (tid - 8) * 8 + 4 + b], (double)red[tid]);
    else if (tid == 12) atomicAdd(&base[p.redo[pl]], (double)red[12]);
  }
}

// in-place transpose over paired 32x32 tiles (triangular task decode)
__global__ __launch_bounds__(256) void k_tipose(TIt p) {
  __shared__ float2 ta[32][33];
  __shared__ float2 tb[32][33];
  int bx = blockIdx.x;
  int pl = 0;
  while (pl + 1 < p.np && bx >= p.toff[pl + 1]) pl++;
  int k = bx - p.toff[pl];
  int N = 1 << p.l2n[pl];
  float2* M = p.pl[pl];
  int ti = (int)((sqrtf(8.0f * (float)k + 1.0f) - 1.0f) * 0.5f);
  while ((ti * (ti + 1)) / 2 > k) ti--;
  while (((ti + 1) * (ti + 2)) / 2 <= k) ti++;
  int tj = k - (ti * (ti + 1)) / 2;
  int tx = threadIdx.x & 31, ty = threadIdx.x >> 5;
  int iy = ti << 5, jx = tj << 5;
  for (int r = ty; r < 32; r += 8) ta[r][tx] = M[(size_t)(iy + r) * N + jx + tx];
  if (ti != tj)
    for (int r = ty; r < 32; r += 8) tb[r][tx] = M[(size_t)(jx + r) * N + iy + tx];
  __syncthreads();
  for (int r = ty; r < 32; r += 8) M[(size_t)(jx + r) * N + iy + tx] = ta[tx][r];
  if (ti != tj)
    for (int r = ty; r < 32; r += 8) M[(size_t)(iy + r) * N + jx + tx] = tb[tx][r];
}

// forward rows-FFT of image + fused raw pixel moments/min/max -> S
__global__ __launch_bounds__(256) void k_fwdA(const float* __restrict__ img, float2* __restrict__ out,
                                              const float2* __restrict__ twg, double* stg, unsigned* stgu) {
  __shared__ float2 shA[1088];
  __shared__ float2 shB[1088];
  __shared__ float2 tw[512];
  __shared__ float red[16];
  int tid = threadIdx.x;
  int part = blockIdx.x & (NP - 1);
  for (int k = tid; k < 512; k += 256) tw[k] = twg[k];
  int row = blockIdx.x;
  float s1 = 0.f, s2 = 0.f, s3 = 0.f, s4 = 0.f;
  float mn = 3.402823466e38f, mx = -3.402823466e38f;
  for (int i = tid; i < 1024; i += 256) {
    float x = img[(size_t)row * 1024 + i];
    shA[skx(i)] = make_float2(x, 0.f);
    float x2 = x * x;
    s1 += x; s2 += x2; s3 += x2 * x; s4 += x2 * x2;
    mn = fminf(mn, x); mx = fmaxf(mx, x);
  }
  float accv[4] = {s1, s2, s3, s4};
  blk_reduce<4>(accv, red);
  if (tid < 4) atomicAdd(&stg[(size_t)part * PSZ + PP_PIX + tid], (double)red[tid]);
  #pragma unroll
  for (int o = 32; o; o >>= 1) { mn = fminf(mn, __shfl_down(mn, o, 64)); mx = fmaxf(mx, __shfl_down(mx, o, 64)); }
  if ((tid & 63) == 0) { atomicMin(&stgu[part * 32 + 1], fkey(mn)); atomicMax(&stgu[part * 32], fkey(mx)); }
  float2* res = fft_core<1024, false>(shA, shB, tw, tid);
  float2* o = out + (size_t)row * 1024;
  for (int i = tid; i < 1024; i += 256) o[i] = res[skx(i)];
}
// forward rows-FFT in place on S (second fft2 pass)
__global__ __launch_bounds__(256) void k_fwdB(float2* S, const float2* __restrict__ twg) {
  __shared__ float2 shA[1088];
  __shared__ float2 shB[1088];
  __shared__ float2 tw[512];
  int tid = threadIdx.x;
  for (int k = tid; k < 512; k += 256) tw[k] = twg[k];
  float2* r = S + (size_t)blockIdx.x * 1024;
  for (int i = tid; i < 1024; i += 256) shA[skx(i)] = r[i];
  __syncthreads();
  float2* res = fft_core<1024, false>(shA, shB, tw, tid);
  for (int i = tid; i < 1024; i += 256) r[i] = res[skx(i)];
}

__global__ __launch_bounds__(256) void k_init(double* stg, unsigned* stgu, float2* Wg) {
  int i = blockIdx.x * 256 + threadIdx.x;
  if (i < NSTG) stg[i] = 0.0;
  if (i < NP) { stgu[i * 32] = 0u; stgu[i * 32 + 1] = 0xFFFFFFFFu; }
  if (i < 512) {
    float a = TWOPI_F * (float)i * (1.0f / 1024.0f);
    float sv, cv; sincosf(a, &sv, &cv);
    Wg[i] = make_float2(cv, sv);
  }
}

// mega autocorr: 21 planes via y-dim; symmetry-halved raw sums; single buffer, high TLP.
// mode 1 planes are (re,mag) packed -> tile value = .y (no sqrt).
__global__ __launch_bounds__(256, 3) void k_autocorr(ACt p, double* acp) {
  __shared__ float tile[40][41];
  __shared__ float fred[4 * 41];
  const int plane = blockIdx.y;
  const int H = 1 << p.l2n[plane];
  const int tpr = H >> 5;
  const int nT = tpr * tpr;
  if ((int)blockIdx.x >= nT) return;
  const float2* __restrict__ in = p.in[plane];
  const int mode = p.mode[plane];
  double* g = acp + ((size_t)((blockIdx.x & (ACPART - 1)) * 21 + p.pi[plane])) * ACSTRIDE;
  float acc[41];
  #pragma unroll
  for (int k = 0; k < 41; k++) acc[k] = 0.f;
  const int tid = threadIdx.x;
  const int tx4 = tid & 7, ty = tid >> 3;
  for (int ti = blockIdx.x; ti < nT; ti += gridDim.x) {
    __syncthreads();
    int by = (ti / tpr) << 5, bx = (ti % tpr) << 5;
    for (int ii = tid; ii < 1600; ii += 256) {
      int r = ii / 40, c = ii - r * 40;
      int gy = (by + r - 4) & (H - 1), gx = (bx + c - 4) & (H - 1);
      float2 v = in[(size_t)gy * H + gx];
      tile[r][c] = mode ? v.y : v.x;
    }
    __syncthreads();
    float r9[8];
    #pragma unroll
    for (int j = 0; j < 8; j++) r9[j] = tile[ty + 4][4 * tx4 + 4 + j];
    float cen[4] = { r9[0], r9[1], r9[2], r9[3] };
    #pragma unroll
    for (int dx = 0; dx <= 4; dx++) {
      float s = 0.f;
      #pragma unroll
      for (int c = 0; c < 4; c++) s += cen[c] * r9[c + dx];
      acc[dx] += s;
    }
    #pragma unroll
    for (int dy = 1; dy <= 4; dy++) {
      float r[12];
      #pragma unroll
      for (int j = 0; j < 12; j++) r[j] = tile[ty + 4 + dy][4 * tx4 + j];
      #pragma unroll
      for (int dx = -4; dx <= 4; dx++) {
        float s = 0.f;
        #pragma unroll
        for (int c = 0; c < 4; c++) s += cen[c] * r[c + dx + 4];
        acc[5 + (dy - 1) * 9 + dx + 4] += s;
      }
    }
  }
  int wave = tid >> 6, lane = tid & 63;
  #pragma unroll
  for (int k = 0; k < 41; k++) {
    float x = acc[k];
    #pragma unroll
    for (int o = 32; o; o >>= 1) x += __shfl_down(x, o, 64);
    if (lane == 0) fred[wave * 41 + k] = x;
  }
  __syncthreads();
  for (int k = tid; k < 41; k += 256)
    atomicAdd(&g[k], (double)(fred[k] + fred[41 + k] + fred[82 + k] + fred[123 + k]));
}

// mega raw Grams: y = scale; band planes are (re,mag) packed
__global__ __launch_bounds__(256, 4) void k_gram4(GRt p, double* stg) {
  __shared__ float red[128];
  int s = blockIdx.y;
  int n = (1024 >> s) * (1024 >> s);
  const float2* b0 = p.bp[s][0]; const float2* b1 = p.bp[s][1];
  const float2* b2 = p.bp[s][2]; const float2* b3 = p.bp[s][3];
  double* base = stg + (size_t)(blockIdx.x & (NP - 1)) * PSZ;
  float acc[32];
  #pragma unroll
  for (int k = 0; k < 32; k++) acc[k] = 0.f;
  for (int i = blockIdx.x * 256 + threadIdx.x; i < n; i += gridDim.x * 256) {
    float2 v0 = b0[i], v1 = b1[i], v2 = b2[i], v3 = b3[i];
    float a[4] = { v0.y, v1.y, v2.y, v3.y };
    float r[4] = { v0.x, v1.x, v2.x, v3.x };
    #pragma unroll
    for (int ii = 0; ii < 4; ii++)
      #pragma unroll
      for (int jj = 0; jj < 4; jj++) { acc[ii * 4 + jj] += a[ii] * a[jj]; acc[16 + ii * 4 + jj] += r[ii] * r[jj]; }
  }
  blk_reduce<32>(acc, red);
  int tid = threadIdx.x;
  if (tid < 16) atomicAdd(&base[PP_C0 + s * 16 + tid], (double)red[tid]);
  else if (tid < 32) atomicAdd(&base[PP_CR + s * 16 + tid - 16], (double)red[tid]);
}

__global__ __launch_bounds__(256, 4) void k_dots_rpar5(const float2* __restrict__ P,
                                                       const float2* __restrict__ b0, const float2* __restrict__ b1,
                                                       const float2* __restrict__ b2, const float2* __restrict__ b3,
                                                       double* stg) {
  __shared__ float red[80];
  double* base = stg + (size_t)(blockIdx.x & (NP - 1)) * PSZ;
  float acc[20];
  #pragma unroll
  for (int k = 0; k < 20; k++) acc[k] = 0.f;
  for (int i = blockIdx.x * 256 + threadIdx.x; i < 16384; i += gridDim.x * 256) {
    int y = i >> 7, x = i & 127;
    float tt[5];
    tt[0] = P[i].x;
    tt[1] = P[(y << 7) | ((x - 1) & 127)].x;
    tt[2] = P[(y << 7) | ((x + 1) & 127)].x;
    tt[3] = P[(((y - 1) & 127) << 7) | x].x;
    tt[4] = P[(((y + 1) & 127) << 7) | x].x;
    float r[4] = { b0[i].x, b1[i].x, b2[i].x, b3[i].x };
    #pragma unroll
    for (int a = 0; a < 4; a++)
      #pragma unroll
      for (int c = 0; c < 5; c++) acc[a * 5 + c] += r[a] * tt[c];
  }
  blk_reduce<20>(acc, red);
  int tid = threadIdx.x;
  if (tid < 20) atomicAdd(&base[PP_CRX + 96 + (tid / 5) * 8 + (tid % 5)], (double)red[tid]);
}
__global__ __launch_bounds__(256, 4) void k_gram5(const float2* __restrict__ P, double* stg) {
  __shared__ float red[100];
  double* base = stg + (size_t)(blockIdx.x & (NP - 1)) * PSZ;
  float acc[25];
  #pragma unroll
  for (int k = 0; k < 25; k++) acc[k] = 0.f;
  for (int i = blockIdx.x * 256 + threadIdx.x; i < 16384; i += gridDim.x * 256) {
    int y = i >> 7, x = i & 127;
    float tt[5];
    tt[0] = P[i].x;
    tt[1] = P[(y << 7) | ((x - 1) & 127)].x;
    tt[2] = P[(y << 7) | ((x + 1) & 127)].x;
    tt[3] = P[(((y - 1) & 127) << 7) | x].x;
    tt[4] = P[(((y + 1) & 127) << 7) | x].x;
    #pragma unroll
    for (int a = 0; a < 5; a++)
      #pragma unroll
      for (int c = 0; c < 5; c++) acc[a * 5 + c] += tt[a] * tt[c];
  }
  blk_reduce<25>(acc, red);
  int tid = threadIdx.x;
  if (tid < 25) atomicAdd(&base[PP_CR5 + tid], (double)red[tid]);
}

// ================= finalize =================
__global__ __launch_bounds__(256) void k_finalize(const double* __restrict__ stg, const unsigned* __restrict__ stgu,
                                                  float* __restrict__ out) {
  int t = blockIdx.x * 256 + threadIdx.x;
  if (t >= 2456) return;
  const double N = 1048576.0;
  auto sumP = [&](int off) -> double {
    double s = 0.0;
    #pragma unroll
    for (int k = 0; k < NP; k++) s += stg[(size_t)k * PSZ + off];
    return s;
  };
  auto sumA = [&](int pi, int so) -> double {
    double s = 0.0;
    #pragma unroll
    for (int pp = 0; pp < ACPART; pp++) s += stg[SG_ACP + (size_t)(pp * 21 + pi) * ACSTRIDE + so];
    return s;
  };
  double m1 = sumP(PP_PIX) / N, m2 = sumP(PP_PIX + 1) / N;
  double vp = m2 - m1 * m1;
  if (t < 6) {
    double m3 = sumP(PP_PIX + 2) / N, m4 = sumP(PP_PIX + 3) / N;
    double cm3 = m3 - 3.0 * m1 * m2 + 2.0 * m1 * m1 * m1;
    double cm4 = m4 - 4.0 * m1 * m3 + 6.0 * m1 * m1 * m2 - 3.0 * m1 * m1 * m1 * m1;
    double r;
    if (t == 0) r = m1;
    else if (t == 1) r = vp * (N / (N - 1.0));
    else if (t == 2) r = cm3 / (vp * sqrt(vp));
    else if (t == 3) r = cm4 / (vp * vp);
    else if (t == 4) {
      unsigned k = 0xFFFFFFFFu;
      for (int i = 0; i < NP; i++) k = min(k, stgu[i * 32 + 1]);
      r = (double)funkey(k);
    } else {
      unsigned k = 0u;
      for (int i = 0; i < NP; i++) k = max(k, stgu[i * 32]);
      r = (double)funkey(k);
    }
    out[t] = (float)r;
  } else if (t < 24) {
    int i = t - 6;
    double csz;
    if (i == 0) csz = 1048576.0;
    else if (i < 17) { int s = (i - 1) >> 2; double h = (double)(1024 >> s); csz = h * h; }
    else csz = 4096.0;
    out[t] = (float)(sumP(PP_MAG + i) / csz);
  } else if (t < 1320) {
    int e = t - 24;
    int b = e & 3, s = (e >> 2) & 3, o = e >> 4;
    double h = (double)(1024 >> s); double csz = h * h;
    double m = sumP(PP_MAG + 1 + 4 * s + b) / csz;
    out[t] = (float)(sumA(s * 4 + b, sidx(o)) / csz - m * m);
  } else if (t < 1330) {
    int kurt = (t >= 1325);
    int s = t - (kurt ? 1325 : 1320);
    double h = (double)(1024 >> s); double csz = h * h;
    double vari = sumP(PP_IMM + s * 3) / csz;
    double var0 = vp * (N / (N - 1.0));
    double v = vari > 1e-12 ? vari : 1e-12;
    double r;
    if (vari / var0 > 1e-6)
      r = kurt ? (sumP(PP_IMM + s * 3 + 2) / csz) / (v * v)
               : (sumP(PP_IMM + s * 3 + 1) / csz) / (v * sqrt(v));
    else
      r = kurt ? 3.0 : 0.0;
    out[t] = (float)r;
  } else if (t < 1735) {
    int e = t - 1330;
    int s = e % 5, o = e / 5;
    double h = (double)(1024 >> s);
    out[t] = (float)(sumA(16 + s, sidx(o)) / (h * h));
  } else if (t < 1815) {
    int e = t - 1735;
    int s = e % 5, o = e / 5;
    if (s < 4) {
      double h = (double)(1024 >> s); double csz = h * h;
      int i = o >> 2, j = o & 3;
      double mi = sumP(PP_MAG + 1 + 4 * s + i) / csz;
      double mj = sumP(PP_MAG + 1 + 4 * s + j) / csz;
      out[t] = (float)(sumP(PP_C0 + s * 16 + o) / csz - mi * mj);
    } else out[t] = 0.0f;
  } else if (t < 1879) {
    int e = t - 1815;
    int s = e & 3, o = e >> 2;
    if (s < 3) {
      double h = (double)(1024 >> s); double csz = h * h;
      int c = o >> 2, b = o & 3;
      double mc = sumP(PP_MAG + 1 + 4 * s + c) / csz;
      double pm = sumP(PP_PMAG + 4 * s + b) / csz;
      out[t] = (float)(sumP(PP_CX + s * 16 + o) / csz - mc * pm);
    } else out[t] = 0.0f;
  } else if (t < 2199) {
    int e = t - 1879;
    int s = e % 5, o = e / 5;
    int i = o >> 3, j = o & 7;
    float r = 0.0f;
    if (s < 4) { if (i < 4 && j < 4) { double h = (double)(1024 >> s); r = (float)(sumP(PP_CR + s * 16 + i * 4 + j) / (h * h)); } }
    else { if (i < 5 && j < 5) r = (float)(sumP(PP_CR5 + i * 5 + j) / 4096.0); }
    out[t] = r;
  } else if (t < 2455) {
    int e = t - 2199;
    int s = e & 3, o = e >> 2;
    int i = o >> 3, j = o & 7;
    float r = 0.0f;
    if (i < 4) {
      if (s < 3) { double h = (double)(1024 >> s); r = (float)(sumP(PP_CRX + s * 32 + i * 8 + j) / (h * h)); }
      else if (j < 5) r = (float)(sumP(PP_CRX + 96 + i * 8 + j) / 16384.0);
    }
    out[t] = r;
  } else {
    out[t] = (float)(sumP(PP_HISQ) / N);
  }
}

// ================= host orchestration =================
extern "C" void kernel_launch(void* const* d_in, const int* in_sizes, int n_in,
                              void* d_out, int out_size, void* d_ws, size_t ws_size,
                              hipStream_t stream) {
  (void)in_sizes; (void)n_in; (void)out_size;
  if (ws_size < 87031808ull) return;
  char* w = (char*)d_ws;
  const float* img = (const float*)d_in[0];
  float* out = (float*)d_out;
  hipStream_t st = stream;

  auto plbytes = [](int l2n) -> size_t { size_t n = (size_t)1 << l2n; return n * n * 8; };
  auto plblocks = [](int l2n) -> int { int N = 1 << l2n; int T = (N >= 1024) ? 256 : ((N >> 2) < 16 ? 16 : (N >> 2)); return N / (256 / T); };
  auto pltasks = [](int l2n) -> int { int T = (1 << l2n) >> 5; return T * (T + 1) / 2; };

  static const signed char PL_L2N[24]  = {10,10,10,10,10,10, 9,9,9,9,9, 8,8,8,8,8, 7,7,7,7,7,7, 6,6};
  static const signed char PL_MODE[24] = {MG_HI, MG_IM, MG_BAND, MG_BAND, MG_BAND, MG_BAND,
                                          MG_IM, MG_BAND, MG_BAND, MG_BAND, MG_BAND,
                                          MG_IM, MG_BAND, MG_BAND, MG_BAND, MG_BAND,
                                          MG_IM, MG_BAND, MG_BAND, MG_BAND, MG_BAND, MG_EMBED_LO,
                                          MG_LORES, MG_IMF4};
  static const signed char PL_SCALE[24] = {0,0,0,0,0,0, 1,1,1,1,1, 2,2,2,2,2, 3,3,3,3,3,4, 4,4};
  static const signed char PL_AUX[24]   = {0,0,0,1,2,3, 0,0,1,2,3, 0,0,1,2,3, 0,0,1,2,3,0, 0,0};
  static const signed char PL_WMODE[24] = {WB_RED_HI, WB_WRITE_IM, WB_WRITE_MAG, WB_WRITE_MAG, WB_WRITE_MAG, WB_WRITE_MAG,
                                           WB_WRITE_IM, WB_WRITE_MAG, WB_WRITE_MAG, WB_WRITE_MAG, WB_WRITE_MAG,
                                           WB_WRITE_IM, WB_WRITE_MAG, WB_WRITE_MAG, WB_WRITE_MAG, WB_WRITE_MAG,
                                           WB_WRITE_IM, WB_WRITE_MAG, WB_WRITE_MAG, WB_WRITE_MAG, WB_WRITE_MAG, WB_WRITE,
                                           WB_RED_ABSRE, WB_WRITE_IM};
  float2* S = (float2*)w;
  size_t off = 8388608ull;
  float2* MP[24];
  for (int p = 0; p < 24; p++) { MP[p] = (float2*)(w + off); off += plbytes(PL_L2N[p]); }
  double* stg = (double*)(w + off); off += (size_t)NSTG * 8;
  unsigned* stgu = (unsigned*)(w + off); off += 4096;
  float2* Wg = (float2*)(w + off); off += 4096;
  char* tail = w + off;

  k_init<<<(NSTG + 255) / 256, 256, 0, st>>>(stg, stgu, Wg);

  k_fwdA<<<1024, 256, 0, st>>>(img, S, Wg, stg, stgu);
  { TIt t{}; t.pl[0] = S; t.l2n[0] = 10; t.toff[0] = 0; t.toff[1] = pltasks(10); t.np = 1;
    k_tipose<<<t.toff[1], 256, 0, st>>>(t); }
  k_fwdB<<<1024, 256, 0, st>>>(S, Wg);

  int redo[24];
  for (int p = 0; p < 24; p++) {
    int s = PL_SCALE[p], b = PL_AUX[p];
    if (PL_WMODE[p] == WB_WRITE_IM) redo[p] = (PL_L2N[p] == 6) ? PP_IMM + 12 : PP_IMM + s * 3;
    else if (PL_WMODE[p] == WB_WRITE_MAG) redo[p] = PP_MAG + 1 + 4 * s + b;
    else if (PL_WMODE[p] == WB_RED_ABSRE) redo[p] = PP_MAG + 17;
    else redo[p] = 0;
  }
  {
    MAt a{}; a.S = S; a.twg = Wg; a.np = 24;
    int bo = 0;
    for (int p = 0; p < 24; p++) {
      a.out[p] = MP[p]; a.boff[p] = bo; bo += plblocks(PL_L2N[p]);
      a.mode[p] = PL_MODE[p]; a.scale[p] = PL_SCALE[p]; a.aux[p] = PL_AUX[p]; a.l2n[p] = PL_L2N[p];
    }
    a.boff[24] = bo;
    k_megaA<<<bo, 256, 0, st>>>(a);
  }
  {
    TIt t{}; t.np = 24;
    int to = 0;
    for (int p = 0; p < 24; p++) { t.pl[p] = MP[p]; t.l2n[p] = PL_L2N[p]; t.toff[p] = to; to += pltasks(PL_L2N[p]); }
    t.toff[24] = to;
    k_tipose<<<to, 256, 0, st>>>(t);
  }
  {
    MBt b{}; b.twg = Wg; b.stg = stg; b.np = 24;
    int bo = 0;
    for (int p = 0; p < 24; p++) {
      b.pl[p] = MP[p]; b.boff[p] = bo; bo += plblocks(PL_L2N[p]);
      b.wmode[p] = PL_WMODE[p]; b.scale[p] = PL_SCALE[p]; b.aux[p] = PL_AUX[p]; b.l2n[p] = PL_L2N[p];
      b.redo[p] = redo[p];
    }
    b.boff[24] = bo;
    k_megaB<<<bo, 256, 0, st>>>(b);
  }
  {
    ACt c{};
    static const signed char AC_PL[21] = {1,2,3,4,5, 6,7,8,9,10, 11,12,13,14,15, 16,17,18,19,20, 23};
    static const signed char AC_PI[21] = {16,0,1,2,3, 17,4,5,6,7, 18,8,9,10,11, 19,12,13,14,15, 20};
    for (int k = 0; k < 21; k++) {
      int p = AC_PL[k];
      c.in[k] = MP[p]; c.pi[k] = AC_PI[k]; c.l2n[k] = PL_L2N[p];
      c.mode[k] = (PL_MODE[p] == MG_BAND) ? 1 : 0;
    }
    k_autocorr<<<dim3(256, 21), 256, 0, st>>>(c, stg + SG_ACP);
  }
  {
    GRt g{};
    static const int BIDX[4][4] = {{2,3,4,5},{7,8,9,10},{12,13,14,15},{17,18,19,20}};
    for (int s = 0; s < 4; s++)
      for (int b4 = 0; b4 < 4; b4++) g.bp[s][b4] = MP[BIDX[s][b4]];
    k_gram4<<<dim3(256, 4), 256, 0, st>>>(g, stg);
  }
  for (int wv = 0; wv < 2; wv++) {
    float2* pp[6];
    signed char pl2[6] = {10, 10, 9, 9, 8, 8};
    signed char psc[6] = {0, 0, 1, 1, 2, 2};
    signed char pax[6];
    pp[0] = MP[0];
    pp[1] = (float2*)tail;
    pp[2] = (float2*)(tail + 8388608ull);
    pp[3] = (float2*)(tail + 8388608ull + 2097152ull);
    pp[4] = (float2*)(tail + 8388608ull + 2 * 2097152ull);
    pp[5] = (float2*)(tail + 8388608ull + 2 * 2097152ull + 524288ull);
    for (int k = 0; k < 6; k++) pax[k] = (signed char)(2 * wv + (k & 1));
    { MAt a{}; a.S = S; a.twg = Wg; a.np = 6;
      int bo = 0;
      for (int k = 0; k < 6; k++) {
        a.out[k] = pp[k]; a.boff[k] = bo; bo += plblocks(pl2[k]);
        a.mode[k] = MG_EMBED_BAND; a.scale[k] = psc[k]; a.aux[k] = pax[k]; a.l2n[k] = pl2[k];
      }
      a.boff[6] = bo;
      k_megaA<<<bo, 256, 0, st>>>(a); }
    { TIt t{}; t.np = 6;
      int to = 0;
      for (int k = 0; k < 6; k++) { t.pl[k] = pp[k]; t.l2n[k] = pl2[k]; t.toff[k] = to; to += pltasks(pl2[k]); }
      t.toff[6] = to;
      k_tipose<<<to, 256, 0, st>>>(t); }
    { MBt b{}; b.twg = Wg; b.stg = stg; b.np = 6;
      static const int BIDX[3][4] = {{2,3,4,5},{7,8,9,10},{12,13,14,15}};
      for (int s = 0; s < 3; s++)
        for (int b4 = 0; b4 < 4; b4++) b.Bp12[s * 4 + b4] = MP[BIDX[s][b4]];
      int bo = 0;
      for (int k = 0; k < 6; k++) {
        b.pl[k] = pp[k]; b.boff[k] = bo; bo += plblocks(pl2[k]);
        b.wmode[k] = WB_PDOTS; b.scale[k] = psc[k]; b.aux[k] = pax[k]; b.l2n[k] = pl2[k];
        b.redo[k] = PP_PMAG + 4 * psc[k] + pax[k];
      }
      b.boff[6] = bo;
      k_megaB<<<bo, 256, 0, st>>>(b); }
  }
  k_dots_rpar5<<<64, 256, 0, st>>>(MP[21], MP[17], MP[18], MP[19], MP[20], stg);
  k_gram5<<<64, 256, 0, st>>>(MP[21], stg);

  k_finalize<<<10, 256, 0, st>>>(stg, stgu, out);
}

// Round 15
// 361.285 us; speedup vs baseline: 1.0257x; 1.0257x over previous
//
#include <hip/hip_runtime.h>
#include <math.h>

#define PI_F      3.14159265358979323846f
#define HALFPI_F  1.57079632679489661923f
#define TWOPI_F   6.28318530717958647692f
#define ANG_F     0.8944271909999159f
#define RT2H      0.70710678118654752f

// ---- staging: [NP partitions][PSZ doubles], partition stride 4KiB ----
#define NP       32
#define PSZ      512
#define PP_PIX   0              // [4]
#define PP_MAG   4              // [18]
#define PP_HISQ  22             // [1]
#define PP_PMAG  23             // [12]
#define PP_IMM   35             // [15]
#define PP_C0    50             // [4][16]
#define PP_CR    114            // [4][16]
#define PP_CX    178            // [3][16]
#define PP_CRX   226            // [4][32]
#define PP_CR5   354            // [25]
#define SG_ACP   (NP * PSZ)
#define ACPART   16
#define ACSTRIDE 64
#define NSTG     (SG_ACP + ACPART * 21 * ACSTRIDE)

enum { MG_HI = 0, MG_IM, MG_BAND, MG_EMBED_BAND, MG_EMBED_LO, MG_LORES, MG_IMF4 };
enum { WB_WRITE = 0, WB_WRITE_MAG, WB_WRITE_IM, WB_RED_HI, WB_RED_ABSRE, WB_PDOTS };

__device__ __forceinline__ int sfreq(int k, int N) { return (k < (N >> 1)) ? k : k - N; }
__device__ __forceinline__ int skx(int i) { return i + (i >> 4); }

// sqrt(rc(x)) = cos(pi/2 * clip(-x,0,1));  sqrt(1-rc(x)) = sin(pi/2 * clip(-x,0,1))
__device__ __forceinline__ float d_clip(float x) { return fminf(fmaxf(-x, 0.0f), 1.0f); }
__device__ __forceinline__ float d_hi(float x) { return __cosf(HALFPI_F * d_clip(x)); }
__device__ __forceinline__ float d_lo(float x) { return __sinf(HALFPI_F * d_clip(x)); }

__device__ __forceinline__ float d_amaskA(int fy, int fx, float rinv, int b) {
  float d;
  if (b == 0)      d = (float)fx;
  else if (b == 1) d = ((float)fx + (float)fy) * RT2H;
  else if (b == 2) d = (float)fy;
  else             d = ((float)fy - (float)fx) * RT2H;
  float c = d * rinv;
  return (c > 0.0f) ? 2.0f * ANG_F * c * c * c : 0.0f;
}
// recon mask at native size H (lr = lograd at H-grid)
__device__ __forceinline__ float d_mm_a(int fy, int fx, int H, float lr, float rinv) {
  float hm = d_hi(lr + 1.0f);
  float hm2 = hm * hm;
  float lo0 = d_lo(lr);
  int gfy = (fy == -(H >> 1)) ? fy : -fy;
  int gfx = (fx == -(H >> 1)) ? fx : -fx;
  float fxc = (float)fx, fyc = (float)fy, gxc = (float)gfx, gyc = (float)gfy;
  float msum = 0.0f;
  #pragma unroll
  for (int b = 0; b < 4; b++) {
    float d1, d2;
    if (b == 0)      { d1 = fxc;                d2 = gxc; }
    else if (b == 1) { d1 = (fxc + fyc) * RT2H; d2 = (gxc + gyc) * RT2H; }
    else if (b == 2) { d1 = fyc;                d2 = gyc; }
    else             { d1 = (fyc - fxc) * RT2H; d2 = (gyc - gxc) * RT2H; }
    float c1 = d1 * rinv, c2 = d2 * rinv;
    float A1 = ANG_F * c1 * c1 * c1;
    float T1 = (c1 > 0.0f) ? A1 : 0.0f;
    float A2 = ANG_F * c2 * c2 * c2;
    float T2 = (c2 > 0.0f) ? A2 : 0.0f;
    msum += A1 * (T1 - T2);
  }
  return lo0 * hm2 * msum;
}
// accumulated im-chain mask at native size 1<<l2n (runtime)
__device__ __forceinline__ float d_G_rt(int fy, int fx, int l2n, float lrb, float rinv) {
  if (fy == 0 && fx == 0) return 0.0f;
  float g = d_mm_a(fy, fx, 1 << l2n, lrb + (float)(1 - l2n), rinv);
  float chain = 1.0f;
  for (int lj = l2n - 1; lj >= 6; lj--) {
    int h = 1 << (lj - 1);
    if (fy < -h || fy >= h || fx < -h || fx >= h) break;
    float lrj = lrb + (float)(1 - lj);
    chain *= d_lo(lrj);
    if (lj > 6) g += chain * d_mm_a(fy, fx, 1 << lj, lrj, rinv);
    else g += chain * d_lo(lrb - 5.0f);
  }
  return g;
}
__device__ __forceinline__ float d_cumlo(float lrb, int s) {
  float m = 1.0f;
  for (int j = 0; j <= s; j++) m *= d_lo(lrb - 9.0f + (float)j);
  return m;
}
__device__ __forceinline__ unsigned fkey(float f) {
  unsigned u = __float_as_uint(f);
  return (u & 0x80000000u) ? ~u : (u | 0x80000000u);
}
__device__ __forceinline__ float funkey(unsigned k) {
  return (k & 0x80000000u) ? __uint_as_float(k & 0x7FFFFFFFu) : __uint_as_float(~k);
}
__device__ __forceinline__ int sidx(int o) {
  int dy = o / 9 - 4, dx = o - (o / 9) * 9 - 4;
  if (dy < 0 || (dy == 0 && dx < 0)) { dy = -dy; dx = -dx; }
  return (dy == 0) ? dx : 5 + (dy - 1) * 9 + dx + 4;
}

template<int K>
__device__ __forceinline__ void blk_reduce(float* v, float* red) {
  int tid = threadIdx.x, wave = tid >> 6, lane = tid & 63;
  #pragma unroll
  for (int k = 0; k < K; k++) {
    float x = v[k];
    #pragma unroll
    for (int o = 32; o; o >>= 1) x += __shfl_down(x, o, 64);
    if (lane == 0) red[wave * K + k] = x;
  }
  __syncthreads();
  if (tid < K) red[tid] = red[tid] + red[K + tid] + red[2 * K + tid] + red[3 * K + tid];
}

// ================= FFT core (Stockham, radix-4 with leading radix-2) =================
template<int N> struct FftConst {
  static constexpr int L2N = (N == 64) ? 6 : (N == 128) ? 7 : (N == 256) ? 8 : (N == 512) ? 9 : 10;
  static constexpr int TPR = (N / 4 >= 256) ? 256 : ((N / 4 < 16) ? 16 : N / 4);
  static constexpr int RPB = 256 / TPR;
  static constexpr int BUF = N + (N >> 4);
};

template<int N, bool INV>
__device__ __forceinline__ float2* fft_core(float2* A, float2* B, const float2* tw, int tr) {
  constexpr int TPR = FftConst<N>::TPR;
  constexpr int L2N = FftConst<N>::L2N;
  float2* src = A; float2* dst = B;
  if constexpr (L2N & 1) {
    for (int t = tr; t < (N >> 1); t += TPR) {
      float2 w = tw[t];
      float cv = w.x, sv = INV ? w.y : -w.y;
      float2 a = src[skx(t)];
      float2 b = src[skx(t + (N >> 1))];
      float dx = a.x - b.x, dy = a.y - b.y;
      dst[skx(2 * t)] = make_float2(a.x + b.x, a.y + b.y);
      dst[skx(2 * t + 1)] = make_float2(dx * cv - dy * sv, dx * sv + dy * cv);
    }
    __syncthreads();
    float2* tmp = src; src = dst; dst = tmp;
  }
  #pragma unroll
  for (int st = (L2N & 1); st < L2N; st += 2) {
    for (int t = tr; t < (N >> 2); t += TPR) {
      int p = t >> st;
      int q = t & ((1 << st) - 1);
      int i0 = q + (p << st);
      float2 x0 = src[skx(i0)];
      float2 x1 = src[skx(i0 + (N >> 2))];
      float2 x2 = src[skx(i0 + (N >> 1))];
      float2 x3 = src[skx(i0 + 3 * (N >> 2))];
      float2 w = tw[p << st];
      float c1 = w.x, s1 = INV ? w.y : -w.y;
      float c2 = c1 * c1 - s1 * s1, s2 = 2.f * c1 * s1;
      float c3 = c2 * c1 - s2 * s1, s3 = c2 * s1 + s2 * c1;
      float e0x = x0.x + x2.x, e0y = x0.y + x2.y;
      float e1x = x0.x - x2.x, e1y = x0.y - x2.y;
      float o0x = x1.x + x3.x, o0y = x1.y + x3.y;
      float d1x = x1.x - x3.x, d1y = x1.y - x3.y;
      float o1x, o1y;
      if constexpr (INV) { o1x = -d1y; o1y = d1x; }
      else               { o1x = d1y;  o1y = -d1x; }
      float t1x = e1x + o1x, t1y = e1y + o1y;
      float t2x = e0x - o0x, t2y = e0y - o0y;
      float t3x = e1x - o1x, t3y = e1y - o1y;
      int o = q + (p << (st + 2));
      int s = 1 << st;
      dst[skx(o)]         = make_float2(e0x + o0x, e0y + o0y);
      dst[skx(o + s)]     = make_float2(t1x * c1 - t1y * s1, t1x * s1 + t1y * c1);
      dst[skx(o + 2 * s)] = make_float2(t2x * c2 - t2y * s2, t2x * s2 + t2y * c2);
      dst[skx(o + 3 * s)] = make_float2(t3x * c3 - t3y * s3, t3x * s3 + t3y * c3);
    }
    __syncthreads();
    float2* tmp = src; src = dst; dst = tmp;
  }
  return src;
}

// ---- mega tables ----
struct MAt {
  const float2* S;
  const float2* twg;
  float2* out[24];
  int boff[25];
  signed char mode[24], scale[24], aux[24], l2n[24];
  int np;
};
struct MBt {
  const float2* twg;
  double* stg;
  float2* pl[24];
  const float2* Bp12[12];
  int boff[25];
  int redo[24];
  signed char wmode[24], scale[24], aux[24], l2n[24];
  int np;
};
struct TIt {
  float2* pl[24];
  int toff[25];
  signed char l2n[24];
  int np;
};
struct ACt { const float2* in[21]; signed char pi[21], mode[21], l2n[21]; };
struct GRt { const float2* bp[4][4]; };

__device__ __forceinline__ float2 loadS(const float2* S, int fy, int fx, int mode, int s, int b, int l2n) {
  if (mode == MG_EMBED_BAND || mode == MG_EMBED_LO) {
    int q = 1 << (l2n - 2);
    if (fy < -q || fy >= q || fx < -q || fx >= q) return make_float2(0.f, 0.f);
  }
  int U = fx >= 0 ? fx : fx + 1024;
  int V = fy >= 0 ? fy : fy + 1024;
  float2 v = S[(size_t)U * 1024 + V];
  float r2 = (float)(fy * fy + fx * fx);
  bool dc = (r2 == 0.0f);
  float lrb = dc ? 0.0f : 0.5f * __log2f(r2);
  float rinv = dc ? 0.0f : rsqrtf(r2);
  float m;
  switch (mode) {
    case MG_HI:
      m = d_hi(lrb - 9.0f);
      return make_float2(v.x * m, v.y * m);
    case MG_IM:
      m = d_cumlo(lrb, s) * d_G_rt(fy, fx, l2n, lrb, rinv);
      return make_float2(v.x * m, v.y * m);
    case MG_BAND:
      m = d_cumlo(lrb, s) * d_hi(lrb + (float)s - 8.0f) * d_amaskA(fy, fx, rinv, b);
      return make_float2(-v.y * m, v.x * m);
    case MG_EMBED_BAND:
      m = d_cumlo(lrb, s + 1) * d_hi(lrb + (float)s - 7.0f) * d_amaskA(fy, fx, rinv, b);
      return make_float2(-v.y * m, v.x * m);
    case MG_EMBED_LO:
    case MG_LORES:
      if (dc) return make_float2(0.f, 0.f);
      m = d_cumlo(lrb, 4);
      return make_float2(v.x * m, v.y * m);
    default:  // MG_IMF4
      if (dc) return make_float2(0.f, 0.f);
      m = d_cumlo(lrb, 4) * d_lo(lrb - 5.0f);
      return make_float2(v.x * m, v.y * m);
  }
}

// mega passA: masked load from S -> inverse row FFT -> write
__global__ __launch_bounds__(256) void k_megaA(MAt p) {
  __shared__ float2 shAB[2176];
  __shared__ float2 tw[512];
  int bx = blockIdx.x;
  int pl = 0;
  while (pl + 1 < p.np && bx >= p.boff[pl + 1]) pl++;
  int rb_ = bx - p.boff[pl];
  int l2n = p.l2n[pl];
  int N = 1 << l2n;
  int TPR = (N >= 1024) ? 256 : ((N >> 2) < 16 ? 16 : (N >> 2));
  int RPB = 256 / TPR;
  int BUF = N + (N >> 4);
  int tid = threadIdx.x;
  for (int k = tid; k < (N >> 1); k += 256) tw[k] = p.twg[k << (10 - l2n)];
  int rl = tid / TPR, tr = tid % TPR;
  int row = rb_ * RPB + rl;
  int mode = p.mode[pl], s = p.scale[pl], b = p.aux[pl];
  float2* A = shAB + rl * BUF;
  float2* Bb = shAB + 1088 + rl * BUF;
  int fx = sfreq(row, N);
  for (int i = tr; i < N; i += TPR) A[skx(i)] = loadS(p.S, sfreq(i, N), fx, mode, s, b, l2n);
  __syncthreads();
  float2* res;
  switch (l2n) {
    case 10: res = fft_core<1024, true>(A, Bb, tw, tr); break;
    case 9:  res = fft_core<512, true>(A, Bb, tw, tr); break;
    case 8:  res = fft_core<256, true>(A, Bb, tw, tr); break;
    case 7:  res = fft_core<128, true>(A, Bb, tw, tr); break;
    default: res = fft_core<64, true>(A, Bb, tw, tr); break;
  }
  float sc = 1.0f / (float)N;
  float2* o = p.out[pl] + (size_t)row * N;
  for (int i = tr; i < N; i += TPR) {
    float2 v = res[skx(i)];
    o[i] = make_float2(v.x * sc, v.y * sc);
  }
}

// mega passB: plain load -> inverse row FFT -> in-place write + fused stats.
// Band planes (WB_WRITE_MAG) are written as (re, mag) pairs: nothing downstream needs im.
__global__ __launch_bounds__(256) void k_megaB(MBt p) {
  __shared__ float2 shAB[2176];
  __shared__ float2 tw[512];
  __shared__ float red[52];
  int bx = blockIdx.x;
  int pl = 0;
  while (pl + 1 < p.np && bx >= p.boff[pl + 1]) pl++;
  int rb_ = bx - p.boff[pl];
  int l2n = p.l2n[pl];
  int N = 1 << l2n;
  int TPR = (N >= 1024) ? 256 : ((N >> 2) < 16 ? 16 : (N >> 2));
  int RPB = 256 / TPR;
  int BUF = N + (N >> 4);
  int tid = threadIdx.x;
  double* base = p.stg + (size_t)(bx & (NP - 1)) * PSZ;
  for (int k = tid; k < (N >> 1); k += 256) tw[k] = p.twg[k << (10 - l2n)];
  int rl = tid / TPR, tr = tid % TPR;
  int row = rb_ * RPB + rl;
  float2* pln = p.pl[pl];
  const float2* in = pln + (size_t)row * N;
  float2* A = shAB + rl * BUF;
  float2* Bb = shAB + 1088 + rl * BUF;
  for (int i = tr; i < N; i += TPR) A[skx(i)] = in[i];
  __syncthreads();
  float2* res;
  switch (l2n) {
    case 10: res = fft_core<1024, true>(A, Bb, tw, tr); break;
    case 9:  res = fft_core<512, true>(A, Bb, tw, tr); break;
    case 8:  res = fft_core<256, true>(A, Bb, tw, tr); break;
    case 7:  res = fft_core<128, true>(A, Bb, tw, tr); break;
    default: res = fft_core<64, true>(A, Bb, tw, tr); break;
  }
  float sc = 1.0f / (float)N;
  int wmode = p.wmode[pl];
  int s = p.scale[pl], b = p.aux[pl];
  if (wmode == WB_WRITE || wmode == WB_WRITE_MAG || wmode == WB_WRITE_IM) {
    float2* o = pln + (size_t)row * N;
    float a0 = 0.f, a1 = 0.f, a2 = 0.f;
    for (int i = tr; i < N; i += TPR) {
      float2 v = res[skx(i)];
      v.x *= sc; v.y *= sc;
      if (wmode == WB_WRITE_MAG) {
        float mag = sqrtf(v.x * v.x + v.y * v.y);
        o[i] = make_float2(v.x, mag);          // (re, mag) pack
        a0 += mag;
      } else {
        o[i] = v;
        if (wmode == WB_WRITE_IM) { float v2 = v.x * v.x; a0 += v2; a1 += v2 * v.x; a2 += v2 * v2; }
      }
    }
    if (wmode == WB_WRITE_MAG) {
      float acc[1] = {a0}; blk_reduce<1>(acc, red);
      if (tid == 0) atomicAdd(&base[p.redo[pl]], (double)red[0]);
    } else if (wmode == WB_WRITE_IM) {
      float acc[3] = {a0, a1, a2}; blk_reduce<3>(acc, red);
      if (tid < 3) atomicAdd(&base[p.redo[pl] + tid], (double)red[tid]);
    }
  } else if (wmode == WB_RED_HI) {
    float a0 = 0.f, a1 = 0.f;
    for (int i = tr; i < N; i += TPR) {
      float v = res[skx(i)].x * sc;
      a0 += fabsf(v); a1 += v * v;
    }
    float acc[2] = {a0, a1}; blk_reduce<2>(acc, red);
    if (tid == 0) atomicAdd(&base[PP_MAG], (double)red[0]);
    if (tid == 1) atomicAdd(&base[PP_HISQ], (double)red[1]);
  } else if (wmode == WB_RED_ABSRE) {
    float a0 = 0.f;
    for (int i = tr; i < N; i += TPR) a0 += fabsf(res[skx(i)].x * sc);
    float acc[1] = {a0}; blk_reduce<1>(acc, red);
    if (tid == 0) atomicAdd(&base[p.redo[pl]], (double)red[0]);
  } else {  // WB_PDOTS (Bp12 planes are (re,mag) packed)
    float acc[13];
    #pragma unroll
    for (int k = 0; k < 13; k++) acc[k] = 0.f;
    for (int i = tr; i < N; i += TPR) {
      float2 v = res[skx(i)];
      v.x *= sc; v.y *= sc;
      float mag = sqrtf(v.x * v.x + v.y * v.y);
      float rr = 0.f, ri = 0.f;
      if (mag > 0.f) { rr = (v.y * v.y - v.x * v.x) / mag; ri = 2.f * v.x * v.y / mag; }
      size_t idx = (size_t)row * N + i;
      #pragma unroll
      for (int c = 0; c < 4; c++) {
        float2 bv = p.Bp12[s * 4 + c][idx];
        acc[c] += bv.y * mag;
        acc[4 + c] += bv.x * rr;
        acc[8 + c] += bv.x * ri;
      }
      acc[12] += mag;
    }
    blk_reduce<13>(acc, red);
    if (tid < 4) atomicAdd(&base[PP_CX + s * 16 + tid * 4 + b], (double)red[tid]);
    else if (tid < 8) atomicAdd(&base[PP_CRX + s * 32 + (tid - 4) * 8 + b], (double)red[tid]);
    else if (tid < 12) atomicAdd(&base[PP_CRX + s * 32 + (tid - 8) * 8 + 4 + b], (double)red[tid]);
    else if (tid == 12) atomicAdd(&base[p.redo[pl]], (double)red[12]);
  }
}

// in-place transpose over paired 32x32 tiles (triangular task decode)
__global__ __launch_bounds__(256) void k_tipose(TIt p) {
  __shared__ float2 ta[32][33];
  __shared__ float2 tb[32][33];
  int bx = blockIdx.x;
  int pl = 0;
  while (pl + 1 < p.np && bx >= p.toff[pl + 1]) pl++;
  int k = bx - p.toff[pl];
  int N = 1 << p.l2n[pl];
  float2* M = p.pl[pl];
  int ti = (int)((sqrtf(8.0f * (float)k + 1.0f) - 1.0f) * 0.5f);
  while ((ti * (ti + 1)) / 2 > k) ti--;
  while (((ti + 1) * (ti + 2)) / 2 <= k) ti++;
  int tj = k - (ti * (ti + 1)) / 2;
  int tx = threadIdx.x & 31, ty = threadIdx.x >> 5;
  int iy = ti << 5, jx = tj << 5;
  for (int r = ty; r < 32; r += 8) ta[r][tx] = M[(size_t)(iy + r) * N + jx + tx];
  if (ti != tj)
    for (int r = ty; r < 32; r += 8) tb[r][tx] = M[(size_t)(jx + r) * N + iy + tx];
  __syncthreads();
  for (int r = ty; r < 32; r += 8) M[(size_t)(jx + r) * N + iy + tx] = ta[tx][r];
  if (ti != tj)
    for (int r = ty; r < 32; r += 8) M[(size_t)(iy + r) * N + jx + tx] = tb[tx][r];
}

// forward rows-FFT of image + fused raw pixel moments/min/max -> S
__global__ __launch_bounds__(256) void k_fwdA(const float* __restrict__ img, float2* __restrict__ out,
                                              const float2* __restrict__ twg, double* stg, unsigned* stgu) {
  __shared__ float2 shA[1088];
  __shared__ float2 shB[1088];
  __shared__ float2 tw[512];
  __shared__ float red[16];
  int tid = threadIdx.x;
  int part = blockIdx.x & (NP - 1);
  for (int k = tid; k < 512; k += 256) tw[k] = twg[k];
  int row = blockIdx.x;
  float s1 = 0.f, s2 = 0.f, s3 = 0.f, s4 = 0.f;
  float mn = 3.402823466e38f, mx = -3.402823466e38f;
  for (int i = tid; i < 1024; i += 256) {
    float x = img[(size_t)row * 1024 + i];
    shA[skx(i)] = make_float2(x, 0.f);
    float x2 = x * x;
    s1 += x; s2 += x2; s3 += x2 * x; s4 += x2 * x2;
    mn = fminf(mn, x); mx = fmaxf(mx, x);
  }
  float accv[4] = {s1, s2, s3, s4};
  blk_reduce<4>(accv, red);
  if (tid < 4) atomicAdd(&stg[(size_t)part * PSZ + PP_PIX + tid], (double)red[tid]);
  #pragma unroll
  for (int o = 32; o; o >>= 1) { mn = fminf(mn, __shfl_down(mn, o, 64)); mx = fmaxf(mx, __shfl_down(mx, o, 64)); }
  if ((tid & 63) == 0) { atomicMin(&stgu[part * 32 + 1], fkey(mn)); atomicMax(&stgu[part * 32], fkey(mx)); }
  float2* res = fft_core<1024, false>(shA, shB, tw, tid);
  float2* o = out + (size_t)row * 1024;
  for (int i = tid; i < 1024; i += 256) o[i] = res[skx(i)];
}
// forward rows-FFT in place on S (second fft2 pass)
__global__ __launch_bounds__(256) void k_fwdB(float2* S, const float2* __restrict__ twg) {
  __shared__ float2 shA[1088];
  __shared__ float2 shB[1088];
  __shared__ float2 tw[512];
  int tid = threadIdx.x;
  for (int k = tid; k < 512; k += 256) tw[k] = twg[k];
  float2* r = S + (size_t)blockIdx.x * 1024;
  for (int i = tid; i < 1024; i += 256) shA[skx(i)] = r[i];
  __syncthreads();
  float2* res = fft_core<1024, false>(shA, shB, tw, tid);
  for (int i = tid; i < 1024; i += 256) r[i] = res[skx(i)];
}

__global__ __launch_bounds__(256) void k_init(double* stg, unsigned* stgu, float2* Wg) {
  int i = blockIdx.x * 256 + threadIdx.x;
  if (i < NSTG) stg[i] = 0.0;
  if (i < NP) { stgu[i * 32] = 0u; stgu[i * 32 + 1] = 0xFFFFFFFFu; }
  if (i < 512) {
    float a = TWOPI_F * (float)i * (1.0f / 1024.0f);
    float sv, cv; sincosf(a, &sv, &cv);
    Wg[i] = make_float2(cv, sv);
  }
}

// mega autocorr: 21 planes via y-dim; symmetry-halved raw sums; single buffer, grid 128.
// mode 1 planes are (re,mag) packed -> tile value = .y (no sqrt).
__global__ __launch_bounds__(256, 3) void k_autocorr(ACt p, double* acp) {
  __shared__ float tile[40][41];
  __shared__ float fred[4 * 41];
  const int plane = blockIdx.y;
  const int H = 1 << p.l2n[plane];
  const int tpr = H >> 5;
  const int nT = tpr * tpr;
  if ((int)blockIdx.x >= nT) return;
  const float2* __restrict__ in = p.in[plane];
  const int mode = p.mode[plane];
  double* g = acp + ((size_t)((blockIdx.x & (ACPART - 1)) * 21 + p.pi[plane])) * ACSTRIDE;
  float acc[41];
  #pragma unroll
  for (int k = 0; k < 41; k++) acc[k] = 0.f;
  const int tid = threadIdx.x;
  const int tx4 = tid & 7, ty = tid >> 3;
  for (int ti = blockIdx.x; ti < nT; ti += gridDim.x) {
    __syncthreads();
    int by = (ti / tpr) << 5, bx = (ti % tpr) << 5;
    for (int ii = tid; ii < 1600; ii += 256) {
      int r = ii / 40, c = ii - r * 40;
      int gy = (by + r - 4) & (H - 1), gx = (bx + c - 4) & (H - 1);
      float2 v = in[(size_t)gy * H + gx];
      tile[r][c] = mode ? v.y : v.x;
    }
    __syncthreads();
    float r9[8];
    #pragma unroll
    for (int j = 0; j < 8; j++) r9[j] = tile[ty + 4][4 * tx4 + 4 + j];
    float cen[4] = { r9[0], r9[1], r9[2], r9[3] };
    #pragma unroll
    for (int dx = 0; dx <= 4; dx++) {
      float s = 0.f;
      #pragma unroll
      for (int c = 0; c < 4; c++) s += cen[c] * r9[c + dx];
      acc[dx] += s;
    }
    #pragma unroll
    for (int dy = 1; dy <= 4; dy++) {
      float r[12];
      #pragma unroll
      for (int j = 0; j < 12; j++) r[j] = tile[ty + 4 + dy][4 * tx4 + j];
      #pragma unroll
      for (int dx = -4; dx <= 4; dx++) {
        float s = 0.f;
        #pragma unroll
        for (int c = 0; c < 4; c++) s += cen[c] * r[c + dx + 4];
        acc[5 + (dy - 1) * 9 + dx + 4] += s;
      }
    }
  }
  int wave = tid >> 6, lane = tid & 63;
  #pragma unroll
  for (int k = 0; k < 41; k++) {
    float x = acc[k];
    #pragma unroll
    for (int o = 32; o; o >>= 1) x += __shfl_down(x, o, 64);
    if (lane == 0) fred[wave * 41 + k] = x;
  }
  __syncthreads();
  for (int k = tid; k < 41; k += 256)
    atomicAdd(&g[k], (double)(fred[k] + fred[41 + k] + fred[82 + k] + fred[123 + k]));
}

// mega raw Grams: y = scale; band planes are (re,mag) packed
__global__ __launch_bounds__(256, 4) void k_gram4(GRt p, double* stg) {
  __shared__ float red[128];
  int s = blockIdx.y;
  int n = (1024 >> s) * (1024 >> s);
  const float2* b0 = p.bp[s][0]; const float2* b1 = p.bp[s][1];
  const float2* b2 = p.bp[s][2]; const float2* b3 = p.bp[s][3];
  double* base = stg + (size_t)(blockIdx.x & (NP - 1)) * PSZ;
  float acc[32];
  #pragma unroll
  for (int k = 0; k < 32; k++) acc[k] = 0.f;
  for (int i = blockIdx.x * 256 + threadIdx.x; i < n; i += gridDim.x * 256) {
    float2 v0 = b0[i], v1 = b1[i], v2 = b2[i], v3 = b3[i];
    float a[4] = { v0.y, v1.y, v2.y, v3.y };
    float r[4] = { v0.x, v1.x, v2.x, v3.x };
    #pragma unroll
    for (int ii = 0; ii < 4; ii++)
      #pragma unroll
      for (int jj = 0; jj < 4; jj++) { acc[ii * 4 + jj] += a[ii] * a[jj]; acc[16 + ii * 4 + jj] += r[ii] * r[jj]; }
  }
  blk_reduce<32>(acc, red);
  int tid = threadIdx.x;
  if (tid < 16) atomicAdd(&base[PP_C0 + s * 16 + tid], (double)red[tid]);
  else if (tid < 32) atomicAdd(&base[PP_CR + s * 16 + tid - 16], (double)red[tid]);
}

__global__ __launch_bounds__(256, 4) void k_dots_rpar5(const float2* __restrict__ P,
                                                       const float2* __restrict__ b0, const float2* __restrict__ b1,
                                                       const float2* __restrict__ b2, const float2* __restrict__ b3,
                                                       double* stg) {
  __shared__ float red[80];
  double* base = stg + (size_t)(blockIdx.x & (NP - 1)) * PSZ;
  float acc[20];
  #pragma unroll
  for (int k = 0; k < 20; k++) acc[k] = 0.f;
  for (int i = blockIdx.x * 256 + threadIdx.x; i < 16384; i += gridDim.x * 256) {
    int y = i >> 7, x = i & 127;
    float tt[5];
    tt[0] = P[i].x;
    tt[1] = P[(y << 7) | ((x - 1) & 127)].x;
    tt[2] = P[(y << 7) | ((x + 1) & 127)].x;
    tt[3] = P[(((y - 1) & 127) << 7) | x].x;
    tt[4] = P[(((y + 1) & 127) << 7) | x].x;
    float r[4] = { b0[i].x, b1[i].x, b2[i].x, b3[i].x };
    #pragma unroll
    for (int a = 0; a < 4; a++)
      #pragma unroll
      for (int c = 0; c < 5; c++) acc[a * 5 + c] += r[a] * tt[c];
  }
  blk_reduce<20>(acc, red);
  int tid = threadIdx.x;
  if (tid < 20) atomicAdd(&base[PP_CRX + 96 + (tid / 5) * 8 + (tid % 5)], (double)red[tid]);
}
__global__ __launch_bounds__(256, 4) void k_gram5(const float2* __restrict__ P, double* stg) {
  __shared__ float red[100];
  double* base = stg + (size_t)(blockIdx.x & (NP - 1)) * PSZ;
  float acc[25];
  #pragma unroll
  for (int k = 0; k < 25; k++) acc[k] = 0.f;
  for (int i = blockIdx.x * 256 + threadIdx.x; i < 16384; i += gridDim.x * 256) {
    int y = i >> 7, x = i & 127;
    float tt[5];
    tt[0] = P[i].x;
    tt[1] = P[(y << 7) | ((x - 1) & 127)].x;
    tt[2] = P[(y << 7) | ((x + 1) & 127)].x;
    tt[3] = P[(((y - 1) & 127) << 7) | x].x;
    tt[4] = P[(((y + 1) & 127) << 7) | x].x;
    #pragma unroll
    for (int a = 0; a < 5; a++)
      #pragma unroll
      for (int c = 0; c < 5; c++) acc[a * 5 + c] += tt[a] * tt[c];
  }
  blk_reduce<25>(acc, red);
  int tid = threadIdx.x;
  if (tid < 25) atomicAdd(&base[PP_CR5 + tid], (double)red[tid]);
}

// ================= finalize =================
__global__ __launch_bounds__(256) void k_finalize(const double* __restrict__ stg, const unsigned* __restrict__ stgu,
                                                  float* __restrict__ out) {
  int t = blockIdx.x * 256 + threadIdx.x;
  if (t >= 2456) return;
  const double N = 1048576.0;
  auto sumP = [&](int off) -> double {
    double s = 0.0;
    #pragma unroll
    for (int k = 0; k < NP; k++) s += stg[(size_t)k * PSZ + off];
    return s;
  };
  auto sumA = [&](int pi, int so) -> double {
    double s = 0.0;
    #pragma unroll
    for (int pp = 0; pp < ACPART; pp++) s += stg[SG_ACP + (size_t)(pp * 21 + pi) * ACSTRIDE + so];
    return s;
  };
  double m1 = sumP(PP_PIX) / N, m2 = sumP(PP_PIX + 1) / N;
  double vp = m2 - m1 * m1;
  if (t < 6) {
    double m3 = sumP(PP_PIX + 2) / N, m4 = sumP(PP_PIX + 3) / N;
    double cm3 = m3 - 3.0 * m1 * m2 + 2.0 * m1 * m1 * m1;
    double cm4 = m4 - 4.0 * m1 * m3 + 6.0 * m1 * m1 * m2 - 3.0 * m1 * m1 * m1 * m1;
    double r;
    if (t == 0) r = m1;
    else if (t == 1) r = vp * (N / (N - 1.0));
    else if (t == 2) r = cm3 / (vp * sqrt(vp));
    else if (t == 3) r = cm4 / (vp * vp);
    else if (t == 4) {
      unsigned k = 0xFFFFFFFFu;
      for (int i = 0; i < NP; i++) k = min(k, stgu[i * 32 + 1]);
      r = (double)funkey(k);
    } else {
      unsigned k = 0u;
      for (int i = 0; i < NP; i++) k = max(k, stgu[i * 32]);
      r = (double)funkey(k);
    }
    out[t] = (float)r;
  } else if (t < 24) {
    int i = t - 6;
    double csz;
    if (i == 0) csz = 1048576.0;
    else if (i < 17) { int s = (i - 1) >> 2; double h = (double)(1024 >> s); csz = h * h; }
    else csz = 4096.0;
    out[t] = (float)(sumP(PP_MAG + i) / csz);
  } else if (t < 1320) {
    int e = t - 24;
    int b = e & 3, s = (e >> 2) & 3, o = e >> 4;
    double h = (double)(1024 >> s); double csz = h * h;
    double m = sumP(PP_MAG + 1 + 4 * s + b) / csz;
    out[t] = (float)(sumA(s * 4 + b, sidx(o)) / csz - m * m);
  } else if (t < 1330) {
    int kurt = (t >= 1325);
    int s = t - (kurt ? 1325 : 1320);
    double h = (double)(1024 >> s); double csz = h * h;
    double vari = sumP(PP_IMM + s * 3) / csz;
    double var0 = vp * (N / (N - 1.0));
    double v = vari > 1e-12 ? vari : 1e-12;
    double r;
    if (vari / var0 > 1e-6)
      r = kurt ? (sumP(PP_IMM + s * 3 + 2) / csz) / (v * v)
               : (sumP(PP_IMM + s * 3 + 1) / csz) / (v * sqrt(v));
    else
      r = kurt ? 3.0 : 0.0;
    out[t] = (float)r;
  } else if (t < 1735) {
    int e = t - 1330;
    int s = e % 5, o = e / 5;
    double h = (double)(1024 >> s);
    out[t] = (float)(sumA(16 + s, sidx(o)) / (h * h));
  } else if (t < 1815) {
    int e = t - 1735;
    int s = e % 5, o = e / 5;
    if (s < 4) {
      double h = (double)(1024 >> s); double csz = h * h;
      int i = o >> 2, j = o & 3;
      double mi = sumP(PP_MAG + 1 + 4 * s + i) / csz;
      double mj = sumP(PP_MAG + 1 + 4 * s + j) / csz;
      out[t] = (float)(sumP(PP_C0 + s * 16 + o) / csz - mi * mj);
    } else out[t] = 0.0f;
  } else if (t < 1879) {
    int e = t - 1815;
    int s = e & 3, o = e >> 2;
    if (s < 3) {
      double h = (double)(1024 >> s); double csz = h * h;
      int c = o >> 2, b = o & 3;
      double mc = sumP(PP_MAG + 1 + 4 * s + c) / csz;
      double pm = sumP(PP_PMAG + 4 * s + b) / csz;
      out[t] = (float)(sumP(PP_CX + s * 16 + o) / csz - mc * pm);
    } else out[t] = 0.0f;
  } else if (t < 2199) {
    int e = t - 1879;
    int s = e % 5, o = e / 5;
    int i = o >> 3, j = o & 7;
    float r = 0.0f;
    if (s < 4) { if (i < 4 && j < 4) { double h = (double)(1024 >> s); r = (float)(sumP(PP_CR + s * 16 + i * 4 + j) / (h * h)); } }
    else { if (i < 5 && j < 5) r = (float)(sumP(PP_CR5 + i * 5 + j) / 4096.0); }
    out[t] = r;
  } else if (t < 2455) {
    int e = t - 2199;
    int s = e & 3, o = e >> 2;
    int i = o >> 3, j = o & 7;
    float r = 0.0f;
    if (i < 4) {
      if (s < 3) { double h = (double)(1024 >> s); r = (float)(sumP(PP_CRX + s * 32 + i * 8 + j) / (h * h)); }
      else if (j < 5) r = (float)(sumP(PP_CRX + 96 + i * 8 + j) / 16384.0);
    }
    out[t] = r;
  } else {
    out[t] = (float)(sumP(PP_HISQ) / N);
  }
}

// ================= host orchestration =================
extern "C" void kernel_launch(void* const* d_in, const int* in_sizes, int n_in,
                              void* d_out, int out_size, void* d_ws, size_t ws_size,
                              hipStream_t stream) {
  (void)in_sizes; (void)n_in; (void)out_size;
  if (ws_size < 87031808ull) return;
  char* w = (char*)d_ws;
  const float* img = (const float*)d_in[0];
  float* out = (float*)d_out;
  hipStream_t st = stream;

  auto plbytes = [](int l2n) -> size_t { size_t n = (size_t)1 << l2n; return n * n * 8; };
  auto plblocks = [](int l2n) -> int { int N = 1 << l2n; int T = (N >= 1024) ? 256 : ((N >> 2) < 16 ? 16 : (N >> 2)); return N / (256 / T); };
  auto pltasks = [](int l2n) -> int { int T = (1 << l2n) >> 5; return T * (T + 1) / 2; };

  static const signed char PL_L2N[24]  = {10,10,10,10,10,10, 9,9,9,9,9, 8,8,8,8,8, 7,7,7,7,7,7, 6,6};
  static const signed char PL_MODE[24] = {MG_HI, MG_IM, MG_BAND, MG_BAND, MG_BAND, MG_BAND,
                                          MG_IM, MG_BAND, MG_BAND, MG_BAND, MG_BAND,
                                          MG_IM, MG_BAND, MG_BAND, MG_BAND, MG_BAND,
                                          MG_IM, MG_BAND, MG_BAND, MG_BAND, MG_BAND, MG_EMBED_LO,
                                          MG_LORES, MG_IMF4};
  static const signed char PL_SCALE[24] = {0,0,0,0,0,0, 1,1,1,1,1, 2,2,2,2,2, 3,3,3,3,3,4, 4,4};
  static const signed char PL_AUX[24]   = {0,0,0,1,2,3, 0,0,1,2,3, 0,0,1,2,3, 0,0,1,2,3,0, 0,0};
  static const signed char PL_WMODE[24] = {WB_RED_HI, WB_WRITE_IM, WB_WRITE_MAG, WB_WRITE_MAG, WB_WRITE_MAG, WB_WRITE_MAG,
                                           WB_WRITE_IM, WB_WRITE_MAG, WB_WRITE_MAG, WB_WRITE_MAG, WB_WRITE_MAG,
                                           WB_WRITE_IM, WB_WRITE_MAG, WB_WRITE_MAG, WB_WRITE_MAG, WB_WRITE_MAG,
                                           WB_WRITE_IM, WB_WRITE_MAG, WB_WRITE_MAG, WB_WRITE_MAG, WB_WRITE_MAG, WB_WRITE,
                                           WB_RED_ABSRE, WB_WRITE_IM};
  float2* S = (float2*)w;
  size_t off = 8388608ull;
  float2* MP[24];
  for (int p = 0; p < 24; p++) { MP[p] = (float2*)(w + off); off += plbytes(PL_L2N[p]); }
  double* stg = (double*)(w + off); off += (size_t)NSTG * 8;
  unsigned* stgu = (unsigned*)(w + off); off += 4096;
  float2* Wg = (float2*)(w + off); off += 4096;
  char* tail = w + off;

  k_init<<<(NSTG + 255) / 256, 256, 0, st>>>(stg, stgu, Wg);

  k_fwdA<<<1024, 256, 0, st>>>(img, S, Wg, stg, stgu);
  { TIt t{}; t.pl[0] = S; t.l2n[0] = 10; t.toff[0] = 0; t.toff[1] = pltasks(10); t.np = 1;
    k_tipose<<<t.toff[1], 256, 0, st>>>(t); }
  k_fwdB<<<1024, 256, 0, st>>>(S, Wg);

  int redo[24];
  for (int p = 0; p < 24; p++) {
    int s = PL_SCALE[p], b = PL_AUX[p];
    if (PL_WMODE[p] == WB_WRITE_IM) redo[p] = (PL_L2N[p] == 6) ? PP_IMM + 12 : PP_IMM + s * 3;
    else if (PL_WMODE[p] == WB_WRITE_MAG) redo[p] = PP_MAG + 1 + 4 * s + b;
    else if (PL_WMODE[p] == WB_RED_ABSRE) redo[p] = PP_MAG + 17;
    else redo[p] = 0;
  }
  {
    MAt a{}; a.S = S; a.twg = Wg; a.np = 24;
    int bo = 0;
    for (int p = 0; p < 24; p++) {
      a.out[p] = MP[p]; a.boff[p] = bo; bo += plblocks(PL_L2N[p]);
      a.mode[p] = PL_MODE[p]; a.scale[p] = PL_SCALE[p]; a.aux[p] = PL_AUX[p]; a.l2n[p] = PL_L2N[p];
    }
    a.boff[24] = bo;
    k_megaA<<<bo, 256, 0, st>>>(a);
  }
  {
    TIt t{}; t.np = 24;
    int to = 0;
    for (int p = 0; p < 24; p++) { t.pl[p] = MP[p]; t.l2n[p] = PL_L2N[p]; t.toff[p] = to; to += pltasks(PL_L2N[p]); }
    t.toff[24] = to;
    k_tipose<<<to, 256, 0, st>>>(t);
  }
  {
    MBt b{}; b.twg = Wg; b.stg = stg; b.np = 24;
    int bo = 0;
    for (int p = 0; p < 24; p++) {
      b.pl[p] = MP[p]; b.boff[p] = bo; bo += plblocks(PL_L2N[p]);
      b.wmode[p] = PL_WMODE[p]; b.scale[p] = PL_SCALE[p]; b.aux[p] = PL_AUX[p]; b.l2n[p] = PL_L2N[p];
      b.redo[p] = redo[p];
    }
    b.boff[24] = bo;
    k_megaB<<<bo, 256, 0, st>>>(b);
  }
  {
    ACt c{};
    static const signed char AC_PL[21] = {1,2,3,4,5, 6,7,8,9,10, 11,12,13,14,15, 16,17,18,19,20, 23};
    static const signed char AC_PI[21] = {16,0,1,2,3, 17,4,5,6,7, 18,8,9,10,11, 19,12,13,14,15, 20};
    for (int k = 0; k < 21; k++) {
      int p = AC_PL[k];
      c.in[k] = MP[p]; c.pi[k] = AC_PI[k]; c.l2n[k] = PL_L2N[p];
      c.mode[k] = (PL_MODE[p] == MG_BAND) ? 1 : 0;
    }
    k_autocorr<<<dim3(128, 21), 256, 0, st>>>(c, stg + SG_ACP);
  }
  {
    GRt g{};
    static const int BIDX[4][4] = {{2,3,4,5},{7,8,9,10},{12,13,14,15},{17,18,19,20}};
    for (int s = 0; s < 4; s++)
      for (int b4 = 0; b4 < 4; b4++) g.bp[s][b4] = MP[BIDX[s][b4]];
    k_gram4<<<dim3(256, 4), 256, 0, st>>>(g, stg);
  }
  for (int wv = 0; wv < 2; wv++) {
    float2* pp[6];
    signed char pl2[6] = {10, 10, 9, 9, 8, 8};
    signed char psc[6] = {0, 0, 1, 1, 2, 2};
    signed char pax[6];
    pp[0] = MP[0];
    pp[1] = (float2*)tail;
    pp[2] = (float2*)(tail + 8388608ull);
    pp[3] = (float2*)(tail + 8388608ull + 2097152ull);
    pp[4] = (float2*)(tail + 8388608ull + 2 * 2097152ull);
    pp[5] = (float2*)(tail + 8388608ull + 2 * 2097152ull + 524288ull);
    for (int k = 0; k < 6; k++) pax[k] = (signed char)(2 * wv + (k & 1));
    { MAt a{}; a.S = S; a.twg = Wg; a.np = 6;
      int bo = 0;
      for (int k = 0; k < 6; k++) {
        a.out[k] = pp[k]; a.boff[k] = bo; bo += plblocks(pl2[k]);
        a.mode[k] = MG_EMBED_BAND; a.scale[k] = psc[k]; a.aux[k] = pax[k]; a.l2n[k] = pl2[k];
      }
      a.boff[6] = bo;
      k_megaA<<<bo, 256, 0, st>>>(a); }
    { TIt t{}; t.np = 6;
      int to = 0;
      for (int k = 0; k < 6; k++) { t.pl[k] = pp[k]; t.l2n[k] = pl2[k]; t.toff[k] = to; to += pltasks(pl2[k]); }
      t.toff[6] = to;
      k_tipose<<<to, 256, 0, st>>>(t); }
    { MBt b{}; b.twg = Wg; b.stg = stg; b.np = 6;
      static const int BIDX[3][4] = {{2,3,4,5},{7,8,9,10},{12,13,14,15}};
      for (int s = 0; s < 3; s++)
        for (int b4 = 0; b4 < 4; b4++) b.Bp12[s * 4 + b4] = MP[BIDX[s][b4]];
      int bo = 0;
      for (int k = 0; k < 6; k++) {
        b.pl[k] = pp[k]; b.boff[k] = bo; bo += plblocks(pl2[k]);
        b.wmode[k] = WB_PDOTS; b.scale[k] = psc[k]; b.aux[k] = pax[k]; b.l2n[k] = pl2[k];
        b.redo[k] = PP_PMAG + 4 * psc[k] + pax[k];
      }
      b.boff[6] = bo;
      k_megaB<<<bo, 256, 0, st>>>(b); }
  }
  k_dots_rpar5<<<64, 256, 0, st>>>(MP[21], MP[17], MP[18], MP[19], MP[20], stg);
  k_gram5<<<64, 256, 0, st>>>(MP[21], stg);

  k_finalize<<<10, 256, 0, st>>>(stg, stgu, out);
}